// Round 1
// baseline (193.960 us; speedup 1.0000x reference)
//
#include <hip/hip_runtime.h>

typedef float f32x4 __attribute__((ext_vector_type(4)));
typedef short s16x8 __attribute__((ext_vector_type(8)));
typedef unsigned int uint;
typedef uint u32x4 __attribute__((ext_vector_type(4)));
typedef uint u32x2 __attribute__((ext_vector_type(2)));

union Frag {
  u32x4 u;
  s16x8 s;
};

// pack two fp32 -> dword of two bf16 (round-half-up via +0x8000)
__device__ __forceinline__ uint packhi(float f0, float f1) {
  uint a = __float_as_uint(f0) + 0x8000u;
  uint b = __float_as_uint(f1) + 0x8000u;
  return __builtin_amdgcn_perm(b, a, 0x07060302u);  // [a.hi16, b.hi16]
}

// split f into bf16 hi + bf16 residual lo; returns packed dwords for a pair
__device__ __forceinline__ void split2(float f0, float f1, uint& hi, uint& lo) {
  uint a0 = __float_as_uint(f0) + 0x8000u;
  uint a1 = __float_as_uint(f1) + 0x8000u;
  hi = __builtin_amdgcn_perm(a1, a0, 0x07060302u);
  float h0 = __uint_as_float(a0 & 0xFFFF0000u);
  float h1 = __uint_as_float(a1 & 0xFFFF0000u);
  lo = packhi(f0 - h0, f1 - h1);
}

// ---- in-register lane-quad transposes (replace all LDS round-trips) ----
// swap32: (a,b) -> ({a[0:32],b[0:32]}, {a[32:64],b[32:64]})
__device__ __forceinline__ u32x2 swap32(uint a, uint b) {
#if __has_builtin(__builtin_amdgcn_permlane32_swap)
  return __builtin_amdgcn_permlane32_swap(a, b, false, false);
#else
  __asm__("v_permlane32_swap_b32 %0, %1" : "+v"(a), "+v"(b));
  u32x2 r;
  r[0] = a;
  r[1] = b;
  return r;
#endif
}
// swap16: per 32-half: (a,b) -> ({a[0:16],b[0:16],a[32:48],b[32:48]},
//                                {a[16:32],b[16:32],a[48:64],b[48:64]})
__device__ __forceinline__ u32x2 swap16(uint a, uint b) {
#if __has_builtin(__builtin_amdgcn_permlane16_swap)
  return __builtin_amdgcn_permlane16_swap(a, b, false, false);
#else
  __asm__("v_permlane16_swap_b32 %0, %1" : "+v"(a), "+v"(b));
  u32x2 r;
  r[0] = a;
  r[1] = b;
  return r;
#endif
}

// B-frag build from C/D: lane (g,lo) holds p = pack(rows 4g,4g+1) and
// q = pack(rows 4g+2,4g+3) of col lo. Produce u[0..3] = row-pairs
// 8gt+{01,23,45,67} of col lo, duplicated across K-halves ([T;T]).
// Quad lanes: L0=lo(g0), L1=lo+16(g1), L2=lo+32(g2), L3=lo+48(g3).
//   u0 = p(L_{2gt}) : swap32(f0,f0) dup-low / dup-high trick gives the
//   [T;T] duplication for free.
__device__ __forceinline__ u32x4 quadB(uint p, uint q) {
  u32x2 e = swap32(p, q);          // e0=[p(L0),p(L1),q(L0),q(L1)] e1=hi-half
  u32x2 f = swap16(e[0], e[1]);    // f0=[p(L0),p(L2),q(L0),q(L2)]
                                   // f1=[p(L1),p(L3),q(L1),q(L3)]
  u32x2 r01 = swap32(f[0], f[0]);  // r01[0]={f0.lo dup}=u0, r01[1]={f0.hi dup}=u1
  u32x2 r23 = swap32(f[1], f[1]);  // u2, u3
  return (u32x4){r01[0], r01[1], r23[0], r23[1]};
}

// A-frag build with K-split [Mh | Ml]: lane (g,lo) holds packed col-pairs
// h0=(4g,4g+1) h1=(4g+2,4g+3) of row lo (hi) and l0,l1 (residual).
// Produce u[j] = cols 8gt+{2j,2j+1} of row lo; hi halves for g<2 (k=0..15),
// residual for g>=2 (k=16..31).
__device__ __forceinline__ u32x4 quadA(uint h0, uint h1, uint l0, uint l1) {
  u32x2 e = swap32(h0, l0);  // e0=[h0(L0),h0(L1),l0(L0),l0(L1)] e1=from L2,L3
  u32x2 g = swap32(h1, l1);
  u32x2 a02 = swap16(e[0], e[1]);  // a02[0]=[h0(L0),h0(L2),l0(L0),l0(L2)]=u0
  u32x2 a13 = swap16(g[0], g[1]);  // a13[0]=u1; a13[1]=u3
  return (u32x4){a02[0], a13[0], a02[1], a13[1]};
}

// E^T = expm(-X)^T in C/D layout, via Horner Taylor order 6 on X^T.
// A operand = [Xh^T | Xl^T] split along K (exact X), B = [Th;Th] duplicated.
// All fragment re-shaping now in-register via permlane quad swaps.
__device__ __forceinline__ f32x4 expm_negT(const float* __restrict__ A, int lo,
                                           int g, int gt, bool low, f32x4 idm) {
  // lane (lo,g) holds A-frag element X^T[lo][8gt+j] = X[8gt+j][lo]
  float c0 = A[(8 * gt + 0) * 16 + lo], c1 = A[(8 * gt + 1) * 16 + lo];
  float c2 = A[(8 * gt + 2) * 16 + lo], c3 = A[(8 * gt + 3) * 16 + lo];
  float c4 = A[(8 * gt + 4) * 16 + lo], c5 = A[(8 * gt + 5) * 16 + lo];
  float c6 = A[(8 * gt + 6) * 16 + lo], c7 = A[(8 * gt + 7) * 16 + lo];
  // X^T in C/D for the affine init: X^T[4g+i][lo] = X[lo][4g+i]
  f32x4 xr = *(const f32x4*)(A + lo * 16 + 4 * g);
  uint h, lw;
  Frag xa;
  split2(c0, c1, h, lw);
  xa.u[0] = low ? h : lw;
  split2(c2, c3, h, lw);
  xa.u[1] = low ? h : lw;
  split2(c4, c5, h, lw);
  xa.u[2] = low ? h : lw;
  split2(c6, c7, h, lw);
  xa.u[3] = low ? h : lw;
  // T = c6*X^T + c5*I  (c_k = (-1)^k/k!)
  f32x4 t;
#pragma unroll
  for (int i = 0; i < 4; ++i)
    t[i] = fmaf(1.f / 720.f, xr[i], (-1.f / 120.f) * idm[i]);
  const float SK[5] = {1.f / 24.f, -1.f / 6.f, 0.5f, -1.f, 1.f};
#pragma unroll
  for (int k = 0; k < 5; ++k) {
    Frag tb;  // B-frag of T, halves duplicated, bit-identical to LDS path
    tb.u = quadB(packhi(t[0], t[1]), packhi(t[2], t[3]));
    f32x4 acc = idm * SK[k];
    t = __builtin_amdgcn_mfma_f32_16x16x32_bf16(xa.s, tb.s, acc, 0, 0, 0);
  }
  return t;  // C/D(expm(-X)^T)
}

__global__ __launch_bounds__(256, 8) void unitary_kernel(
    const float* __restrict__ x, float* __restrict__ out) {
  const int tid = threadIdx.x;
  const int w = tid >> 6;
  const int l = tid & 63;
  const int lo = l & 15;
  const int g = l >> 4;
  const int gt = g & 1;
  const bool low = g < 2;

  const int ch = blockIdx.x * 4 + w;  // chain 0..8191
  const float* xb =
      x + ((size_t)(127 - (ch >> 6)) * 1024 + (size_t)(ch & 63) * 16) * 256;

  f32x4 idm;
  idm[0] = (4 * g + 0 == lo) ? 1.f : 0.f;
  idm[1] = (4 * g + 1 == lo) ? 1.f : 0.f;
  idm[2] = (4 * g + 2 == lo) ? 1.f : 0.f;
  idm[3] = (4 * g + 3 == lo) ? 1.f : 0.f;

  // B-frag of identity, halves duplicated ([I;I]) — pairs with split-A
  Frag ifr;
  {
    uint v = ((lo >> 3) == gt) ? (0x3F80u << (16 * (lo & 1))) : 0u;
    int slot = (lo >> 1) & 3;
    ifr.u[0] = (slot == 0) ? v : 0u;
    ifr.u[1] = (slot == 1) ? v : 0u;
    ifr.u[2] = (slot == 2) ? v : 0u;
    ifr.u[3] = (slot == 3) ? v : 0u;
  }

  f32x4 uc;
#pragma unroll 1
  for (int j = 0; j < 16; ++j) {
    f32x4 et = expm_negT(xb + j * 256, lo, g, gt, low, idm);
    // A-frag(E) = [Eh | El] split along K, from E^T C/D packs
    uint eh0, el0, eh1, el1;
    split2(et[0], et[1], eh0, el0);
    split2(et[2], et[3], eh1, el1);
    Frag ea;
    ea.u = quadA(eh0, eh1, el0, el1);
    f32x4 z = {0.f, 0.f, 0.f, 0.f};
    if (j) {
      // B-frags of U: [Uh;Uh] and [Ul;Ul] from U C/D packs
      uint uh0, ul0, uh1, ul1;
      split2(uc[0], uc[1], uh0, ul0);
      split2(uc[2], uc[3], uh1, ul1);
      Frag b1, b2;
      b1.u = quadB(uh0, uh1);
      b2.u = quadB(ul0, ul1);
      f32x4 t1 = __builtin_amdgcn_mfma_f32_16x16x32_bf16(ea.s, b1.s, z, 0, 0, 0);
      uc = __builtin_amdgcn_mfma_f32_16x16x32_bf16(ea.s, b2.s, t1, 0, 0, 0);
    } else {
      uc = __builtin_amdgcn_mfma_f32_16x16x32_bf16(ea.s, ifr.s, z, 0, 0, 0);
    }
  }

  // store U (C/D -> row-major), coalesced 64B segments per quarter-wave
  float* op = out + (size_t)ch * 256;
  op[(4 * g + 0) * 16 + lo] = uc[0];
  op[(4 * g + 1) * 16 + lo] = uc[1];
  op[(4 * g + 2) * 16 + lo] = uc[2];
  op[(4 * g + 3) * 16 + lo] = uc[3];
}

extern "C" void kernel_launch(void* const* d_in, const int* in_sizes, int n_in,
                              void* d_out, int out_size, void* d_ws,
                              size_t ws_size, hipStream_t stream) {
  const float* x = (const float*)d_in[0];
  float* out = (float*)d_out;
  unitary_kernel<<<dim3(2048), dim3(256), 0, stream>>>(x, out);
}

// Round 2
// 192.327 us; speedup vs baseline: 1.0085x; 1.0085x over previous
//
#include <hip/hip_runtime.h>

typedef float f32x4 __attribute__((ext_vector_type(4)));
typedef short s16x8 __attribute__((ext_vector_type(8)));
typedef unsigned int uint;
typedef uint u32x4 __attribute__((ext_vector_type(4)));
typedef uint u32x2 __attribute__((ext_vector_type(2)));

union Frag {
  u32x4 u;
  s16x8 s;
};

// pack two fp32 -> dword of two bf16 (round-half-up via +0x8000)
__device__ __forceinline__ uint packhi(float f0, float f1) {
  uint a = __float_as_uint(f0) + 0x8000u;
  uint b = __float_as_uint(f1) + 0x8000u;
  return __builtin_amdgcn_perm(b, a, 0x07060302u);  // [a.hi16, b.hi16]
}

// truncating split: f -> bf16 hi (truncate) + bf16 residual lo (truncate).
// Valid ONLY where both halves enter the MFMA (exactness-preserving pair):
// hi+lo represents f to ~2^-16 rel either way, so rounding hi is pointless.
// 6 VALU ops vs 10 for the rounding version.
__device__ __forceinline__ void splitT2(float f0, float f1, uint& hi,
                                        uint& lo) {
  uint a0 = __float_as_uint(f0);
  uint a1 = __float_as_uint(f1);
  hi = __builtin_amdgcn_perm(a1, a0, 0x07060302u);
  float r0 = f0 - __uint_as_float(a0 & 0xFFFF0000u);
  float r1 = f1 - __uint_as_float(a1 & 0xFFFF0000u);
  lo = __builtin_amdgcn_perm(__float_as_uint(r1), __float_as_uint(r0),
                             0x07060302u);
}

// compiler-only memory fence: orders DS write before DS read in the emitted
// stream; HW executes same-wave DS ops in order, no s_waitcnt needed between.
#define CFENCE() __asm__ __volatile__("" ::: "memory")

// ---- in-register lane-quad transposes (Horner path only; VALU pipe) ----
__device__ __forceinline__ u32x2 swap32(uint a, uint b) {
#if __has_builtin(__builtin_amdgcn_permlane32_swap)
  return __builtin_amdgcn_permlane32_swap(a, b, false, false);
#else
  __asm__("v_permlane32_swap_b32 %0, %1" : "+v"(a), "+v"(b));
  u32x2 r;
  r[0] = a;
  r[1] = b;
  return r;
#endif
}
__device__ __forceinline__ u32x2 swap16(uint a, uint b) {
#if __has_builtin(__builtin_amdgcn_permlane16_swap)
  return __builtin_amdgcn_permlane16_swap(a, b, false, false);
#else
  __asm__("v_permlane16_swap_b32 %0, %1" : "+v"(a), "+v"(b));
  u32x2 r;
  r[0] = a;
  r[1] = b;
  return r;
#endif
}

// B-frag build from C/D packs (rows 4g..4g+3 of col lo as two dwords p,q)
// -> u[0..3] = row-pairs 8gt+{01,23,45,67} of col lo, dup across K-halves.
__device__ __forceinline__ u32x4 quadB(uint p, uint q) {
  u32x2 e = swap32(p, q);
  u32x2 f = swap16(e[0], e[1]);
  u32x2 r01 = swap32(f[0], f[0]);  // dup-lo / dup-hi trick: [T;T] for free
  u32x2 r23 = swap32(f[1], f[1]);
  return (u32x4){r01[0], r01[1], r23[0], r23[1]};
}

// E^T = expm(-X)^T in C/D layout, via Horner Taylor order 6 on X^T.
// A operand = [Xh^T | Xl^T] split along K (exact X), B = [Th;Th] duplicated.
// Horner B-frag reshaping on the VALU pipe (permlane); chain reshaping in
// the caller uses the LDS pipe — splits the load across both pipes.
__device__ __forceinline__ f32x4 expm_negT(const float* __restrict__ A, int lo,
                                           int g, int gt, bool low, f32x4 idm,
                                           f32x4 idm120) {
  // lane (lo,g) holds A-frag element X^T[lo][8gt+j] = X[8gt+j][lo]
  float c0 = A[(8 * gt + 0) * 16 + lo], c1 = A[(8 * gt + 1) * 16 + lo];
  float c2 = A[(8 * gt + 2) * 16 + lo], c3 = A[(8 * gt + 3) * 16 + lo];
  float c4 = A[(8 * gt + 4) * 16 + lo], c5 = A[(8 * gt + 5) * 16 + lo];
  float c6 = A[(8 * gt + 6) * 16 + lo], c7 = A[(8 * gt + 7) * 16 + lo];
  // X^T in C/D for the affine init: X^T[4g+i][lo] = X[lo][4g+i]
  f32x4 xr = *(const f32x4*)(A + lo * 16 + 4 * g);
  uint h, lw;
  Frag xa;
  splitT2(c0, c1, h, lw);
  xa.u[0] = low ? h : lw;
  splitT2(c2, c3, h, lw);
  xa.u[1] = low ? h : lw;
  splitT2(c4, c5, h, lw);
  xa.u[2] = low ? h : lw;
  splitT2(c6, c7, h, lw);
  xa.u[3] = low ? h : lw;
  // T = c6*X^T + c5*I  (c_k = (-1)^k/k!)
  f32x4 t;
#pragma unroll
  for (int i = 0; i < 4; ++i) t[i] = fmaf(1.f / 720.f, xr[i], idm120[i]);
  const float SK[5] = {1.f / 24.f, -1.f / 6.f, 0.5f, -1.f, 1.f};
#pragma unroll
  for (int k = 0; k < 5; ++k) {
    Frag tb;  // B-frag of T (rounded bf16 — this residual IS dropped)
    tb.u = quadB(packhi(t[0], t[1]), packhi(t[2], t[3]));
    f32x4 acc = idm * SK[k];
    t = __builtin_amdgcn_mfma_f32_16x16x32_bf16(xa.s, tb.s, acc, 0, 0, 0);
  }
  return t;  // C/D(expm(-X)^T)
}

__global__ __launch_bounds__(256, 8) void unitary_kernel(
    const float* __restrict__ x, float* __restrict__ out) {
  __shared__ uint PE[4][320];  // chain E staging: {h0,h1,l0,l1} stride 20
  __shared__ uint PU[4][320];  // chain U staging: {h0,h1,l0,l1} stride 20

  const int tid = threadIdx.x;
  const int w = tid >> 6;
  const int l = tid & 63;
  const int lo = l & 15;
  const int g = l >> 4;
  const int gt = g & 1;
  const bool low = g < 2;

  uint* pe = PE[w];
  uint* pu = PU[w];

  const int ch = blockIdx.x * 4 + w;  // chain 0..8191
  const float* xb =
      x + ((size_t)(127 - (ch >> 6)) * 1024 + (size_t)(ch & 63) * 16) * 256;

  f32x4 idm;
  idm[0] = (4 * g + 0 == lo) ? 1.f : 0.f;
  idm[1] = (4 * g + 1 == lo) ? 1.f : 0.f;
  idm[2] = (4 * g + 2 == lo) ? 1.f : 0.f;
  idm[3] = (4 * g + 3 == lo) ? 1.f : 0.f;
  f32x4 idm120 = idm * (-1.f / 120.f);

  // B-frag of identity, halves duplicated ([I;I]) — pairs with split-A
  Frag ifr;
  {
    uint v = ((lo >> 3) == gt) ? (0x3F80u << (16 * (lo & 1))) : 0u;
    int slot = (lo >> 1) & 3;
    ifr.u[0] = (slot == 0) ? v : 0u;
    ifr.u[1] = (slot == 1) ? v : 0u;
    ifr.u[2] = (slot == 2) ? v : 0u;
    ifr.u[3] = (slot == 3) ? v : 0u;
  }

  uint* pew = pe + lo * 20 + 4 * g;
  const uint* pea = pe + lo * 20 + 8 * gt + (low ? 0 : 2);
  uint* puw = pu + lo * 20 + 4 * g;
  const uint* pub = pu + lo * 20 + 8 * gt;

  f32x4 uc;
#pragma unroll 1
  for (int j = 0; j < 16; ++j) {
    f32x4 et = expm_negT(xb + j * 256, lo, g, gt, low, idm, idm120);
    uint h0, l0, h1, l1;
    splitT2(et[0], et[1], h0, l0);
    splitT2(et[2], et[3], h1, l1);
    *(u32x4*)pew = (u32x4){h0, h1, l0, l1};
    if (j) {
      splitT2(uc[0], uc[1], h0, l0);
      splitT2(uc[2], uc[3], h1, l1);
      *(u32x4*)puw = (u32x4){h0, h1, l0, l1};
    }
    CFENCE();
    // A-frag(E) = B-frag(E^T): k-regroup, hi for g<2, lo residual for g>=2
    Frag ea;
    ea.u[0] = pea[0];
    ea.u[1] = pea[1];
    ea.u[2] = pea[4];
    ea.u[3] = pea[5];
    f32x4 z = {0.f, 0.f, 0.f, 0.f};
    if (j) {
      Frag b1, b2;  // [Uh;Uh] and [Ul;Ul]
      b1.u[0] = pub[0];
      b1.u[1] = pub[1];
      b1.u[2] = pub[4];
      b1.u[3] = pub[5];
      b2.u[0] = pub[2];
      b2.u[1] = pub[3];
      b2.u[2] = pub[6];
      b2.u[3] = pub[7];
      CFENCE();
      f32x4 t1 =
          __builtin_amdgcn_mfma_f32_16x16x32_bf16(ea.s, b1.s, z, 0, 0, 0);
      uc = __builtin_amdgcn_mfma_f32_16x16x32_bf16(ea.s, b2.s, t1, 0, 0, 0);
    } else {
      CFENCE();
      uc = __builtin_amdgcn_mfma_f32_16x16x32_bf16(ea.s, ifr.s, z, 0, 0, 0);
    }
  }

  // store U (C/D -> row-major), coalesced 64B segments per quarter-wave
  float* op = out + (size_t)ch * 256;
  op[(4 * g + 0) * 16 + lo] = uc[0];
  op[(4 * g + 1) * 16 + lo] = uc[1];
  op[(4 * g + 2) * 16 + lo] = uc[2];
  op[(4 * g + 3) * 16 + lo] = uc[3];
}

extern "C" void kernel_launch(void* const* d_in, const int* in_sizes, int n_in,
                              void* d_out, int out_size, void* d_ws,
                              size_t ws_size, hipStream_t stream) {
  const float* x = (const float*)d_in[0];
  float* out = (float*)d_out;
  unitary_kernel<<<dim3(2048), dim3(256), 0, stream>>>(x, out);
}

// Round 4
// 191.283 us; speedup vs baseline: 1.0140x; 1.0055x over previous
//
#include <hip/hip_runtime.h>

typedef float f32x4 __attribute__((ext_vector_type(4)));
typedef short s16x8 __attribute__((ext_vector_type(8)));
typedef unsigned int uint;
typedef uint u32x4 __attribute__((ext_vector_type(4)));
typedef uint u32x2 __attribute__((ext_vector_type(2)));

union Frag {
  u32x4 u;
  s16x8 s;
};

// pack two fp32 -> dword of two bf16 (round-half-up via +0x8000)
// PROVEN path (rounds 0-2) — do not replace with hand-written cvt_pk.
__device__ __forceinline__ uint packhi(float f0, float f1) {
  uint a = __float_as_uint(f0) + 0x8000u;
  uint b = __float_as_uint(f1) + 0x8000u;
  return __builtin_amdgcn_perm(b, a, 0x07060302u);  // [b.hi16, a.hi16]
}

// truncating split: f -> bf16 hi (truncate) + bf16 residual lo (truncate).
// Valid ONLY where both halves enter the MFMA (exactness-preserving pair).
__device__ __forceinline__ void splitT2(float f0, float f1, uint& hi,
                                        uint& lo) {
  uint a0 = __float_as_uint(f0);
  uint a1 = __float_as_uint(f1);
  hi = __builtin_amdgcn_perm(a1, a0, 0x07060302u);
  float r0 = f0 - __uint_as_float(a0 & 0xFFFF0000u);
  float r1 = f1 - __uint_as_float(a1 & 0xFFFF0000u);
  lo = __builtin_amdgcn_perm(__float_as_uint(r1), __float_as_uint(r0),
                             0x07060302u);
}

// compiler-only memory fence: orders DS write before DS read in the emitted
// stream; HW executes same-wave DS ops in order, no s_waitcnt needed between.
#define CFENCE() __asm__ __volatile__("" ::: "memory")

// ---- in-register lane-quad transposes (Horner path only; VALU pipe) ----
__device__ __forceinline__ u32x2 swap32(uint a, uint b) {
#if __has_builtin(__builtin_amdgcn_permlane32_swap)
  return __builtin_amdgcn_permlane32_swap(a, b, false, false);
#else
  __asm__("v_permlane32_swap_b32 %0, %1" : "+v"(a), "+v"(b));
  u32x2 r;
  r[0] = a;
  r[1] = b;
  return r;
#endif
}
__device__ __forceinline__ u32x2 swap16(uint a, uint b) {
#if __has_builtin(__builtin_amdgcn_permlane16_swap)
  return __builtin_amdgcn_permlane16_swap(a, b, false, false);
#else
  __asm__("v_permlane16_swap_b32 %0, %1" : "+v"(a), "+v"(b));
  u32x2 r;
  r[0] = a;
  r[1] = b;
  return r;
#endif
}

// B-frag build from C/D packs (rows 4g..4g+3 of col lo as two dwords p,q)
// -> u[0..3] = row-pairs 8gt+{01,23,45,67} of col lo, dup across K-halves.
__device__ __forceinline__ u32x4 quadB(uint p, uint q) {
  u32x2 e = swap32(p, q);
  u32x2 f = swap16(e[0], e[1]);
  u32x2 r01 = swap32(f[0], f[0]);  // dup-lo / dup-hi trick: [T;T] for free
  u32x2 r23 = swap32(f[1], f[1]);
  return (u32x4){r01[0], r01[1], r23[0], r23[1]};
}

__global__ __launch_bounds__(256, 8) void unitary_kernel(
    const float* __restrict__ x, float* __restrict__ out) {
  __shared__ uint PE[4][320];  // chain E staging: {h0,h1,l0,l1} stride 20
  __shared__ uint PU[4][320];  // chain U staging: {h0,h1,l0,l1} stride 20

  const int tid = threadIdx.x;
  const int w = tid >> 6;
  const int l = tid & 63;
  const int lo = l & 15;
  const int g = l >> 4;
  const int gt = g & 1;
  const bool low = g < 2;

  uint* pe = PE[w];
  uint* pu = PU[w];

  // chain index is wave-uniform: pin to SGPR so x/out addressing is
  // s-base + v-offset (frees VGPR pairs for the prefetch state)
  const int ch = __builtin_amdgcn_readfirstlane(blockIdx.x * 4 + w);
  const float* xb =
      x + ((size_t)(127 - (ch >> 6)) * 1024 + (size_t)(ch & 63) * 16) * 256;

  f32x4 idm;
  idm[0] = (4 * g + 0 == lo) ? 1.f : 0.f;
  idm[1] = (4 * g + 1 == lo) ? 1.f : 0.f;
  idm[2] = (4 * g + 2 == lo) ? 1.f : 0.f;
  idm[3] = (4 * g + 3 == lo) ? 1.f : 0.f;
  f32x4 idm120 = idm * (-1.f / 120.f);

  // B-frag of identity, halves duplicated ([I;I]) — pairs with split-A
  Frag ifr;
  {
    uint v = ((lo >> 3) == gt) ? (0x3F80u << (16 * (lo & 1))) : 0u;
    int slot = (lo >> 1) & 3;
    ifr.u[0] = (slot == 0) ? v : 0u;
    ifr.u[1] = (slot == 1) ? v : 0u;
    ifr.u[2] = (slot == 2) ? v : 0u;
    ifr.u[3] = (slot == 3) ? v : 0u;
  }

  uint* pew = pe + lo * 20 + 4 * g;
  const uint* pea = pe + lo * 20 + 8 * gt + (low ? 0 : 2);
  uint* puw = pu + lo * 20 + 4 * g;
  const uint* pub = pu + lo * 20 + 8 * gt;

  // preload j=0: column dwords (A-frag source) + row dwordx4 (affine init)
  const int coff = 8 * gt * 16 + lo;  // element (8gt)*16+lo
  float c0 = xb[coff + 0 * 16], c1 = xb[coff + 1 * 16];
  float c2 = xb[coff + 2 * 16], c3 = xb[coff + 3 * 16];
  float c4 = xb[coff + 4 * 16], c5 = xb[coff + 5 * 16];
  float c6 = xb[coff + 6 * 16], c7 = xb[coff + 7 * 16];
  f32x4 xr = *(const f32x4*)(xb + lo * 16 + 4 * g);

  f32x4 uc;
#pragma unroll 1
  for (int j = 0; j < 16; ++j) {
    // ---- expm(-X)^T, Horner Taylor order 6 on X^T ----
    // A operand = [Xh^T | Xl^T] split along K (exact X), B = [Th;Th] dup.
    uint h, lw;
    Frag xa;
    splitT2(c0, c1, h, lw);
    xa.u[0] = low ? h : lw;
    splitT2(c2, c3, h, lw);
    xa.u[1] = low ? h : lw;
    splitT2(c4, c5, h, lw);
    xa.u[2] = low ? h : lw;
    splitT2(c6, c7, h, lw);
    xa.u[3] = low ? h : lw;
    // T = c6*X^T + c5*I  (c_k = (-1)^k/k!)
    f32x4 t;
#pragma unroll
    for (int i = 0; i < 4; ++i) t[i] = fmaf(1.f / 720.f, xr[i], idm120[i]);

    // ---- prefetch next matrix now: latency hides under Horner + chain ----
    // (j==15 wraps to 0 — harmless L1-hot re-read, avoids a branch)
    const float* xn = xb + (((j + 1) & 15) * 256);
    float n0 = xn[coff + 0 * 16], n1 = xn[coff + 1 * 16];
    float n2 = xn[coff + 2 * 16], n3 = xn[coff + 3 * 16];
    float n4 = xn[coff + 4 * 16], n5 = xn[coff + 5 * 16];
    float n6 = xn[coff + 6 * 16], n7 = xn[coff + 7 * 16];
    f32x4 nxr = *(const f32x4*)(xn + lo * 16 + 4 * g);

    const float SK[5] = {1.f / 24.f, -1.f / 6.f, 0.5f, -1.f, 1.f};
#pragma unroll
    for (int k = 0; k < 5; ++k) {
      Frag tb;  // B-frag of T (rounded bf16 — this residual IS dropped)
      tb.u = quadB(packhi(t[0], t[1]), packhi(t[2], t[3]));
      f32x4 acc = idm * SK[k];
      t = __builtin_amdgcn_mfma_f32_16x16x32_bf16(xa.s, tb.s, acc, 0, 0, 0);
    }
    // t = C/D(expm(-X)^T)

    // ---- chain step: U <- E * U (LDS pipe for the reshapes) ----
    uint h0, l0, h1, l1;
    splitT2(t[0], t[1], h0, l0);
    splitT2(t[2], t[3], h1, l1);
    *(u32x4*)pew = (u32x4){h0, h1, l0, l1};
    if (j) {
      splitT2(uc[0], uc[1], h0, l0);
      splitT2(uc[2], uc[3], h1, l1);
      *(u32x4*)puw = (u32x4){h0, h1, l0, l1};
    }
    CFENCE();
    // A-frag(E) = B-frag(E^T): k-regroup, hi for g<2, lo residual for g>=2
    Frag ea;
    ea.u[0] = pea[0];
    ea.u[1] = pea[1];
    ea.u[2] = pea[4];
    ea.u[3] = pea[5];
    f32x4 z = {0.f, 0.f, 0.f, 0.f};
    if (j) {
      Frag b1, b2;  // [Uh;Uh] and [Ul;Ul]
      b1.u[0] = pub[0];
      b1.u[1] = pub[1];
      b1.u[2] = pub[4];
      b1.u[3] = pub[5];
      b2.u[0] = pub[2];
      b2.u[1] = pub[3];
      b2.u[2] = pub[6];
      b2.u[3] = pub[7];
      CFENCE();
      f32x4 t1 =
          __builtin_amdgcn_mfma_f32_16x16x32_bf16(ea.s, b1.s, z, 0, 0, 0);
      uc = __builtin_amdgcn_mfma_f32_16x16x32_bf16(ea.s, b2.s, t1, 0, 0, 0);
    } else {
      CFENCE();
      uc = __builtin_amdgcn_mfma_f32_16x16x32_bf16(ea.s, ifr.s, z, 0, 0, 0);
    }

    // rotate prefetched registers into place
    c0 = n0; c1 = n1; c2 = n2; c3 = n3;
    c4 = n4; c5 = n5; c6 = n6; c7 = n7;
    xr = nxr;
  }

  // store U (C/D -> row-major), coalesced 64B segments per quarter-wave
  float* op = out + (size_t)ch * 256;
  op[(4 * g + 0) * 16 + lo] = uc[0];
  op[(4 * g + 1) * 16 + lo] = uc[1];
  op[(4 * g + 2) * 16 + lo] = uc[2];
  op[(4 * g + 3) * 16 + lo] = uc[3];
}

extern "C" void kernel_launch(void* const* d_in, const int* in_sizes, int n_in,
                              void* d_out, int out_size, void* d_ws,
                              size_t ws_size, hipStream_t stream) {
  const float* x = (const float*)d_in[0];
  float* out = (float*)d_out;
  unitary_kernel<<<dim3(2048), dim3(256), 0, stream>>>(x, out);
}